// Round 4
// baseline (153.721 us; speedup 1.0000x reference)
//
#include <hip/hip_runtime.h>
#include <hip/hip_fp16.h>

// SAGEConv mean-aggr: out_i = mean_{j->i} x_j @ W_l^T + b_l + x_i @ W_r^T
//
// R1-R9: see journal. 481 -> 132.45 us via counting-sort + LDS u64 atomics,
//        VGPR weights, 2-blocks/CU agg.
// R10: hl as 8xfp16 -> neutral. R11: reg prefetch refused by compiler.
// R12: DMA staging + barriers -> neutral. THREE proj rewrites all land at
//      41-42 us => invariant is not proj code: (a) scatter blocks co-resident
//      serialize the shared TA (4096 divergent 4B stores/block); (b) agg
//      (~30 us, hidden below fill cutoff) is bound by 3 ds_add_u64/edge,
//      which is why R10's gather-halving was null.
// R13: (1) SPLIT proj / scatter / agg into separate dispatches (attribution
//          + unmix TA traffic);
//      (2) proj: barrier-free per-WAVE DMA pipeline (private 2x4KB dbuf,
//          vmcnt(4) counted waits, no s_barrier);
//      (3) agg: in-LDS counting sort to per-node CSR (1 u32 LDS atomic/edge)
//          + exact fp32 register accumulation. Zero u64 atomics.

#define N_NODES 100000
#define N_EDGES 1600000
#define D_IN 128

#define HR_STRIDE 8
#define N_PAD 100352                   // padded node count

#define B_NODES 196                    // nodes per bucket
#define N_BUCKETS 512                  // 512*196 = 100352 >= N_NODES
#define CAP 3840                       // mean 3125, sigma ~56 -> +12.8 sigma

#define SC_EPT 8
#define SC_EPB (256 * SC_EPT)          // 2048 edges per scatter block
#define SC_GRID ((N_EDGES + SC_EPB - 1) / SC_EPB)   // 782

#define PROJ_NPB 128                   // nodes per proj block (4 waves x 32)
#define PROJ_BLOCKS ((N_NODES + PROJ_NPB - 1) / PROJ_NPB)   // 782

typedef unsigned long long u64;
typedef unsigned int u32;

__device__ __forceinline__ float dot8(const float4 a0, const float4 a1,
                                      const float4 b0, const float4 b1) {
    return a0.x * b0.x + a0.y * b0.y + a0.z * b0.z + a0.w * b0.w
         + a1.x * b1.x + a1.y * b1.y + a1.z * b1.z + a1.w * b1.w;
}

// ---------------------------------------------------------------------------
// Kernel 1: projection. Per-wave autonomous DMA pipeline, no barriers.
// Each wave: 32 nodes in 4 batches of 8, 2 batches (8 KB) in flight.
// ---------------------------------------------------------------------------
__global__ __launch_bounds__(256, 4) void proj_kernel(
    const float* __restrict__ x,
    const float* __restrict__ Wl,
    const float* __restrict__ Wr,
    uint4* __restrict__ hl,             // [N_PAD] 8xfp16 packed, first 5 valid
    float* __restrict__ hr)             // [N_PAD][8] f32, first 5 valid
{
    __shared__ __align__(16) char xb[4][2][4096];   // [wave][dbuf] = 32 KB

    const int tid  = threadIdx.x;
    const int wvi  = tid >> 6;          // wave 0..3
    const int lane = tid & 63;
    const int g    = lane >> 4;         // 16-lane group in wave, 0..3
    const int k    = lane & 15;         // dims [8k, 8k+8)

    const int wnode0 = blockIdx.x * PROJ_NPB + wvi * 32;
    const char* xbytes = (const char*)x;
    const size_t XLIM = (size_t)N_NODES * 512 - 16;

    float4 wv[10][2];
#pragma unroll
    for (int o = 0; o < 10; ++o) {
        const float* w = (o < 5 ? Wl + o * D_IN : Wr + (o - 5) * D_IN) + k * 8;
        wv[o][0] = ((const float4*)w)[0];
        wv[o][1] = ((const float4*)w)[1];
    }

    // stage 8 nodes (4 KB) of batch into this wave's buffer bufi.
    // dest = wave-uniform base + lane*16 (linear), 4 insts of 1 KB.
#define PSTAGE(bufi, batch)                                                  \
    {                                                                        \
        const size_t gb0 = (size_t)(wnode0 + (batch) * 8) * 512;             \
        _Pragma("unroll")                                                    \
        for (int r = 0; r < 4; ++r) {                                        \
            const int loff = r * 1024 + lane * 16;                           \
            size_t goff = gb0 + (size_t)loff;                                \
            goff = goff > XLIM ? XLIM : goff;                                \
            __builtin_amdgcn_global_load_lds(                                \
                (const __attribute__((address_space(1))) void*)(xbytes + goff), \
                (__attribute__((address_space(3))) void*)(&xb[wvi][bufi][loff]), \
                16, 0, 0);                                                   \
        }                                                                    \
    }

    PSTAGE(0, 0);
    PSTAGE(1, 1);

#pragma unroll
    for (int b = 0; b < 4; ++b) {
        if (b == 3) asm volatile("s_waitcnt vmcnt(0)" ::: "memory");
        else        asm volatile("s_waitcnt vmcnt(4)" ::: "memory");

        const char* xc = &xb[wvi][b & 1][0];
#pragma unroll
        for (int u = 0; u < 2; ++u) {
            const int nlb  = g * 2 + u;                 // node in batch 0..7
            const int node = wnode0 + b * 8 + nlb;      // may be >=N (pad row)
            const float4* xp = (const float4*)(xc + nlb * 512 + k * 32);
            float4 x0 = xp[0];
            float4 x1 = xp[1];

            float s[10];
#pragma unroll
            for (int o = 0; o < 10; ++o)
                s[o] = dot8(x0, x1, wv[o][0], wv[o][1]);

#pragma unroll
            for (int o = 0; o < 10; ++o) {
                s[o] += __shfl_xor(s[o], 8, 64);
                s[o] += __shfl_xor(s[o], 4, 64);
                s[o] += __shfl_xor(s[o], 2, 64);
                s[o] += __shfl_xor(s[o], 1, 64);
            }

            if (k == 0) {
                u32 u0 = (u32)__half_as_ushort(__float2half_rn(s[0]));
                u32 u1 = (u32)__half_as_ushort(__float2half_rn(s[1]));
                u32 u2 = (u32)__half_as_ushort(__float2half_rn(s[2]));
                u32 u3 = (u32)__half_as_ushort(__float2half_rn(s[3]));
                u32 u4 = (u32)__half_as_ushort(__float2half_rn(s[4]));
                uint4 pk;
                pk.x = u0 | (u1 << 16);
                pk.y = u2 | (u3 << 16);
                pk.z = u4;
                pk.w = 0u;
                hl[node] = pk;

                float* pr = hr + (size_t)node * HR_STRIDE;
                *(float4*)pr = make_float4(s[5], s[6], s[7], s[8]);
                pr[4] = s[9];
            }
        }
        if (b < 2) {
            // buf b&1 fully consumed by this wave (no other wave touches it)
            asm volatile("s_waitcnt lgkmcnt(0)" ::: "memory");
            PSTAGE(b & 1, b + 2);
        }
    }
#undef PSTAGE
}

// ---------------------------------------------------------------------------
// Kernel 2: counting-sort scatter of edges into 512 dst-buckets.
// ---------------------------------------------------------------------------
__global__ __launch_bounds__(256) void scatter_kernel(
    const int* __restrict__ ei,         // [2][N_EDGES]: row0 src, row1 dst
    u32* __restrict__ sorted,           // [N_BUCKETS][CAP]
    int* __restrict__ cursor)           // [N_BUCKETS], zero-initialized
{
    __shared__ int hist[N_BUCKETS];
    __shared__ int basepos[N_BUCKETS];

    const int tid = threadIdx.x;
    for (int i = tid; i < N_BUCKETS; i += 256) hist[i] = 0;
    __syncthreads();

    const int e0 = blockIdx.x * SC_EPB + tid * SC_EPT;

    int srcv[SC_EPT], dstv[SC_EPT], slot[SC_EPT];
    bool valid[SC_EPT];

    if (e0 + SC_EPT <= N_EDGES) {
        const int4* s4 = (const int4*)(ei + e0);
        const int4* d4 = (const int4*)(ei + N_EDGES + e0);
#pragma unroll
        for (int c = 0; c < SC_EPT / 4; ++c) {
            int4 sv = s4[c], dv = d4[c];
            srcv[c*4+0] = sv.x; srcv[c*4+1] = sv.y;
            srcv[c*4+2] = sv.z; srcv[c*4+3] = sv.w;
            dstv[c*4+0] = dv.x; dstv[c*4+1] = dv.y;
            dstv[c*4+2] = dv.z; dstv[c*4+3] = dv.w;
        }
#pragma unroll
        for (int q = 0; q < SC_EPT; ++q) valid[q] = true;
    } else {
#pragma unroll
        for (int q = 0; q < SC_EPT; ++q) {
            int e = e0 + q;
            valid[q] = (e < N_EDGES);
            srcv[q] = valid[q] ? ei[e] : 0;
            dstv[q] = valid[q] ? ei[N_EDGES + e] : 0;
        }
    }

#pragma unroll
    for (int q = 0; q < SC_EPT; ++q) {
        if (valid[q]) {
            unsigned b = (unsigned)dstv[q] / 196u;   // magic-mul div
            slot[q] = atomicAdd(&hist[b], 1);
        }
    }
    __syncthreads();

    for (int b = tid; b < N_BUCKETS; b += 256) {
        int c = hist[b];
        if (c > 0) basepos[b] = atomicAdd(&cursor[b], c);
    }
    __syncthreads();

#pragma unroll
    for (int q = 0; q < SC_EPT; ++q) {
        if (valid[q]) {
            unsigned b = (unsigned)dstv[q] / 196u;
            unsigned r = (unsigned)dstv[q] - b * 196u;
            sorted[(size_t)b * CAP + basepos[b] + slot[q]] =
                (r << 17) | (unsigned)srcv[q];
        }
    }
}

// ---------------------------------------------------------------------------
// Kernel 3: aggregation. Per bucket: in-LDS counting sort by node-in-bucket
// (1 u32 LDS atomic/edge), then exact fp32 register accumulation with 2
// threads per node. Zero u64 atomics.
// ---------------------------------------------------------------------------
#define AGG_T 512

__global__ __launch_bounds__(512) void agg_kernel(
    const u32* __restrict__ sorted,
    const int* __restrict__ cursor,
    const uint4* __restrict__ hl,
    const float* __restrict__ hr,
    const float* __restrict__ bias,
    float* __restrict__ out)
{
    __shared__ u32 hist[B_NODES];       // atomic slot counter
    __shared__ u32 deg[B_NODES];        // final per-node degree
    __shared__ u32 offs[B_NODES];       // scan buffer -> exclusive offsets
    __shared__ u32 srcs[CAP];           // node-sorted src list (15.4 KB)
    __shared__ float part[B_NODES][5];  // portion-1 partials

    const int b   = blockIdx.x;
    const int tid = threadIdx.x;

    for (int i = tid; i < B_NODES; i += AGG_T) hist[i] = 0u;
    __syncthreads();

    const int cnt = min(cursor[b], CAP);
    const u32* sp = sorted + (size_t)b * CAP;

    // phase A: read edges (coalesced), LDS-histogram, remember slots in regs
    u32 ev[8];
    int rv[8], sl[8];
#pragma unroll
    for (int q = 0; q < 8; ++q) {
        int i = tid + q * AGG_T;
        ev[q] = (i < cnt) ? sp[i] : 0xFFFFFFFFu;    // valid entries < 196<<17
    }
#pragma unroll
    for (int q = 0; q < 8; ++q) {
        if (ev[q] != 0xFFFFFFFFu) {
            rv[q] = (int)(ev[q] >> 17);
            sl[q] = (int)atomicAdd(&hist[rv[q]], 1u);
        }
    }
    __syncthreads();

    // phase B: copy hist->deg, inclusive Hillis-Steele scan in offs,
    // convert to exclusive
    if (tid < B_NODES) { deg[tid] = hist[tid]; offs[tid] = hist[tid]; }
    __syncthreads();
#pragma unroll
    for (int s = 1; s < B_NODES; s <<= 1) {
        u32 v = 0;
        if (tid < B_NODES && tid >= s) v = offs[tid - s];
        __syncthreads();
        if (tid < B_NODES) offs[tid] += v;
        __syncthreads();
    }
    if (tid < B_NODES) offs[tid] -= deg[tid];
    __syncthreads();

    // phase C: scatter srcs into per-node CSR segments in LDS
#pragma unroll
    for (int q = 0; q < 8; ++q) {
        if (ev[q] != 0xFFFFFFFFu)
            srcs[offs[rv[q]] + (u32)sl[q]] = ev[q] & 0x1FFFFu;
    }
    __syncthreads();

    // phase D: accumulate. threads [0,196) = portion 0, [196,392) = portion 1
    float a0 = 0.f, a1 = 0.f, a2 = 0.f, a3 = 0.f, a4 = 0.f;
    if (tid < 2 * B_NODES) {
        const int p = (tid >= B_NODES);
        const int n = p ? tid - B_NODES : tid;
        const u32 d = deg[n];
        const u32 o = offs[n];
        const u32 h0 = (d + 1) >> 1;
        const u32 i0 = p ? o + h0 : o;
        const u32 i1 = p ? o + d : o + h0;
        for (u32 i = i0; i < i1; ++i) {
            u32 s = srcs[i];
            uint4 h = hl[s];
            a0 += __half2float(__ushort_as_half((unsigned short)(h.x & 0xFFFFu)));
            a1 += __half2float(__ushort_as_half((unsigned short)(h.x >> 16)));
            a2 += __half2float(__ushort_as_half((unsigned short)(h.y & 0xFFFFu)));
            a3 += __half2float(__ushort_as_half((unsigned short)(h.y >> 16)));
            a4 += __half2float(__ushort_as_half((unsigned short)(h.z & 0xFFFFu)));
        }
        if (p) {
            part[n][0] = a0; part[n][1] = a1; part[n][2] = a2;
            part[n][3] = a3; part[n][4] = a4;
        }
    }
    __syncthreads();

    // phase E: combine portions, mean, add bias + hr, store
    if (tid < B_NODES) {
        const int node = b * B_NODES + tid;
        if (node < N_NODES) {
            a0 += part[tid][0]; a1 += part[tid][1]; a2 += part[tid][2];
            a3 += part[tid][3]; a4 += part[tid][4];
            const float rec = 1.0f / fmaxf((float)deg[tid], 1.0f);
            const float* h = hr + (size_t)node * HR_STRIDE;
            float* o = out + (size_t)node * 5;
            o[0] = a0 * rec + bias[0] + h[0];
            o[1] = a1 * rec + bias[1] + h[1];
            o[2] = a2 * rec + bias[2] + h[2];
            o[3] = a3 * rec + bias[3] + h[3];
            o[4] = a4 * rec + bias[4] + h[4];
        }
    }
}

extern "C" void kernel_launch(void* const* d_in, const int* in_sizes, int n_in,
                              void* d_out, int out_size, void* d_ws, size_t ws_size,
                              hipStream_t stream) {
    const float* x    = (const float*)d_in[0];
    const int*   ei   = (const int*)d_in[1];
    const float* Wl   = (const float*)d_in[2];
    const float* bl   = (const float*)d_in[3];
    const float* Wr   = (const float*)d_in[4];
    float*       out  = (float*)d_out;

    // workspace layout (16B-aligned): ~12.7 MB total
    uint4* hl     = (uint4*)d_ws;                                 // N_PAD*16 B
    float* hr     = (float*)(hl + N_PAD);                         // N_PAD*8 f
    u32*   sorted = (u32*)(hr + (size_t)N_PAD * HR_STRIDE);       // 512*3840 u32
    int*   cursor = (int*)(sorted + (size_t)N_BUCKETS * CAP);     // 512 i32

    hipMemsetAsync(cursor, 0, N_BUCKETS * sizeof(int), stream);

    proj_kernel<<<PROJ_BLOCKS, 256, 0, stream>>>(x, Wl, Wr, hl, hr);
    scatter_kernel<<<SC_GRID, 256, 0, stream>>>(ei, sorted, cursor);
    agg_kernel<<<N_BUCKETS, 512, 0, stream>>>(sorted, cursor, hl, hr, bl, out);
}

// Round 6
// 131.765 us; speedup vs baseline: 1.1666x; 1.1666x over previous
//
#include <hip/hip_runtime.h>
#include <hip/hip_fp16.h>

// SAGEConv mean-aggr: out_i = mean_{j->i} x_j @ W_l^T + b_l + x_i @ W_r^T
//
// R1-R9: 481 -> 132.45 us (counting-sort buckets + LDS u64 atomics, VGPR
//        weights, 2-blocks/CU agg).
// R10: hl as 8xfp16 -> neutral (agg not gather-bound).
// R11: fused proj+scatter 2:1 interleave, EPT16 -> 127.7 us. BEST.
// R12: DMA-staged proj -> neutral (42.6). Proj NEVER moves fused-A: the
//      fused makespan is scatter-set; proj rides under it for free.
// R13: split into 3 dispatches -> 153.7 us REGRESSION: same-stream kernels
//      serialize; the split destroyed proj/scatter overlap. Lesson: keep
//      independent phases fused via blockIdx partitioning.
// R14: recombine: R11's fused proj+scatter (measured 41.28) + R13's
//      zero-u64-atomic agg (in-LDS counting sort -> CSR -> exact fp32
//      accumulation, 1 u32 LDS atomic/edge). Single variable vs R11:
//      agg_new - agg_old.
// R15: R14 never ran (container infra failure, no counters). Resubmitting
//      unchanged to preserve the controlled experiment.

#define N_NODES 100000
#define N_EDGES 1600000
#define D_IN 128

#define HR_STRIDE 8
#define N_PAD 100352                   // padded node count

#define B_NODES 196                    // nodes per bucket
#define N_BUCKETS 512                  // 512*196 = 100352 >= N_NODES
#define CAP 3840                       // mean 3125, sigma ~56 -> +12.8 sigma

#define SC_EPT 16
#define SC_EPB (256 * SC_EPT)          // 4096 edges per scatter block
#define SC_GRID ((N_EDGES + SC_EPB - 1) / SC_EPB)   // 391

#define PROJ_NPB 128                   // nodes per proj block
#define PROJ_BLOCKS ((N_NODES + PROJ_NPB - 1) / PROJ_NPB)   // 782
// interleave 2 proj : 1 scatter; PROJ_BLOCKS == 2*SC_GRID == 782
#define FUSED_GRID (PROJ_BLOCKS + SC_GRID)                  // 1173

typedef unsigned long long u64;
typedef unsigned int u32;

__device__ __forceinline__ float dot8(const float4 a0, const float4 a1,
                                      const float4 b0, const float4 b1) {
    return a0.x * b0.x + a0.y * b0.y + a0.z * b0.z + a0.w * b0.w
         + a1.x * b1.x + a1.y * b1.y + a1.z * b1.z + a1.w * b1.w;
}

// ---------------------------------------------------------------------------
// Fused kernel A: interleaved projection (2 of 3 blocks) + counting-sort
// scatter (1 of 3). Exactly the R11 kernel (measured 41.28 us).
// ---------------------------------------------------------------------------
__global__ __launch_bounds__(256, 4) void proj_scatter_kernel(
    const float* __restrict__ x,
    const float* __restrict__ Wl,
    const float* __restrict__ Wr,
    uint4* __restrict__ hl,             // [N_PAD] 8xfp16 packed, first 5 valid
    float* __restrict__ hr,             // [N_PAD][8] f32, first 5 valid
    const int* __restrict__ ei,         // [2][N_EDGES]: row0 src, row1 dst
    u32* __restrict__ sorted,           // [N_BUCKETS][CAP]
    int* __restrict__ cursor)           // [N_BUCKETS], zero-initialized
{
    const int tid = threadIdx.x;
    const int m   = blockIdx.x % 3;
    const int d   = blockIdx.x / 3;

    if (m < 2) {
        // ---------------- projection ----------------
        const int pidx = d * 2 + m;      // 0..781
        const int g = tid >> 4;          // group 0..15
        const int k = tid & 15;          // lane within group, dims [8k,8k+8)
        const int node0 = pidx * PROJ_NPB + g * 8;

#pragma unroll
        for (int hb = 0; hb < 2; ++hb) {
            const int nb = node0 + hb * 4;

            float4 xv[4][2];
            int nodes[4];
#pragma unroll
            for (int it = 0; it < 4; ++it) {
                nodes[it] = min(nb + it, N_NODES - 1);
                const float4* xr =
                    (const float4*)(x + (size_t)nodes[it] * D_IN + k * 8);
                xv[it][0] = xr[0];
                xv[it][1] = xr[1];
            }

            // Wl pass
            {
                float4 wv[5][2];
#pragma unroll
                for (int o = 0; o < 5; ++o) {
                    const float* w = Wl + o * D_IN + k * 8;
                    wv[o][0] = ((const float4*)w)[0];
                    wv[o][1] = ((const float4*)w)[1];
                }
#pragma unroll
                for (int it = 0; it < 4; ++it) {
                    float s[5];
#pragma unroll
                    for (int o = 0; o < 5; ++o)
                        s[o] = dot8(xv[it][0], xv[it][1], wv[o][0], wv[o][1]);
#pragma unroll
                    for (int o = 0; o < 5; ++o) {
                        s[o] += __shfl_xor(s[o], 8, 64);
                        s[o] += __shfl_xor(s[o], 4, 64);
                        s[o] += __shfl_xor(s[o], 2, 64);
                        s[o] += __shfl_xor(s[o], 1, 64);
                    }
                    if (k == 0) {
                        u32 u0 = (u32)__half_as_ushort(__float2half_rn(s[0]));
                        u32 u1 = (u32)__half_as_ushort(__float2half_rn(s[1]));
                        u32 u2 = (u32)__half_as_ushort(__float2half_rn(s[2]));
                        u32 u3 = (u32)__half_as_ushort(__float2half_rn(s[3]));
                        u32 u4 = (u32)__half_as_ushort(__float2half_rn(s[4]));
                        uint4 pk;
                        pk.x = u0 | (u1 << 16);
                        pk.y = u2 | (u3 << 16);
                        pk.z = u4;
                        pk.w = 0u;
                        hl[nodes[it]] = pk;
                    }
                }
            }

            // Wr pass
            {
                float4 wv[5][2];
#pragma unroll
                for (int o = 0; o < 5; ++o) {
                    const float* w = Wr + o * D_IN + k * 8;
                    wv[o][0] = ((const float4*)w)[0];
                    wv[o][1] = ((const float4*)w)[1];
                }
#pragma unroll
                for (int it = 0; it < 4; ++it) {
                    float s[5];
#pragma unroll
                    for (int o = 0; o < 5; ++o)
                        s[o] = dot8(xv[it][0], xv[it][1], wv[o][0], wv[o][1]);
#pragma unroll
                    for (int o = 0; o < 5; ++o) {
                        s[o] += __shfl_xor(s[o], 8, 64);
                        s[o] += __shfl_xor(s[o], 4, 64);
                        s[o] += __shfl_xor(s[o], 2, 64);
                        s[o] += __shfl_xor(s[o], 1, 64);
                    }
                    if (k == 0) {
                        float* pr = hr + (size_t)nodes[it] * HR_STRIDE;
                        *(float4*)pr = make_float4(s[0], s[1], s[2], s[3]);
                        pr[4] = s[4];
                    }
                }
            }
        }
    } else {
        // ---------------- counting-sort scatter ----------------
        __shared__ int hist[N_BUCKETS];
        __shared__ int basepos[N_BUCKETS];

        for (int i = tid; i < N_BUCKETS; i += 256) hist[i] = 0;
        __syncthreads();

        const int e0 = d * SC_EPB + tid * SC_EPT;

        int srcv[SC_EPT], dstv[SC_EPT], slot[SC_EPT];
        bool valid[SC_EPT];

        if (e0 + SC_EPT <= N_EDGES) {
            const int4* s4 = (const int4*)(ei + e0);
            const int4* d4 = (const int4*)(ei + N_EDGES + e0);
#pragma unroll
            for (int c = 0; c < SC_EPT / 4; ++c) {
                int4 sv = s4[c], dv = d4[c];
                srcv[c*4+0] = sv.x; srcv[c*4+1] = sv.y;
                srcv[c*4+2] = sv.z; srcv[c*4+3] = sv.w;
                dstv[c*4+0] = dv.x; dstv[c*4+1] = dv.y;
                dstv[c*4+2] = dv.z; dstv[c*4+3] = dv.w;
            }
#pragma unroll
            for (int q = 0; q < SC_EPT; ++q) valid[q] = true;
        } else {
#pragma unroll
            for (int q = 0; q < SC_EPT; ++q) {
                int e = e0 + q;
                valid[q] = (e < N_EDGES);
                srcv[q] = valid[q] ? ei[e] : 0;
                dstv[q] = valid[q] ? ei[N_EDGES + e] : 0;
            }
        }

#pragma unroll
        for (int q = 0; q < SC_EPT; ++q) {
            if (valid[q]) {
                unsigned b = (unsigned)dstv[q] / 196u;   // magic-mul div
                slot[q] = atomicAdd(&hist[b], 1);
            }
        }
        __syncthreads();

        for (int b = tid; b < N_BUCKETS; b += 256) {
            int c = hist[b];
            if (c > 0) basepos[b] = atomicAdd(&cursor[b], c);
        }
        __syncthreads();

#pragma unroll
        for (int q = 0; q < SC_EPT; ++q) {
            if (valid[q]) {
                unsigned b = (unsigned)dstv[q] / 196u;
                unsigned r = (unsigned)dstv[q] - b * 196u;
                sorted[(size_t)b * CAP + basepos[b] + slot[q]] =
                    (r << 17) | (unsigned)srcv[q];
            }
        }
    }
}

// ---------------------------------------------------------------------------
// Kernel B: aggregation. Per bucket: in-LDS counting sort by node-in-bucket
// (1 u32 LDS atomic/edge), then exact fp32 register accumulation with 2
// threads per node. Zero u64 atomics.
// ---------------------------------------------------------------------------
#define AGG_T 512

__global__ __launch_bounds__(512) void agg_kernel(
    const u32* __restrict__ sorted,
    const int* __restrict__ cursor,
    const uint4* __restrict__ hl,
    const float* __restrict__ hr,
    const float* __restrict__ bias,
    float* __restrict__ out)
{
    __shared__ u32 hist[B_NODES];       // atomic slot counter
    __shared__ u32 deg[B_NODES];        // final per-node degree
    __shared__ u32 offs[B_NODES];       // scan buffer -> exclusive offsets
    __shared__ u32 srcs[CAP];           // node-sorted src list (15.4 KB)
    __shared__ float part[B_NODES][5];  // portion-1 partials

    const int b   = blockIdx.x;
    const int tid = threadIdx.x;

    for (int i = tid; i < B_NODES; i += AGG_T) hist[i] = 0u;
    __syncthreads();

    const int cnt = min(cursor[b], CAP);
    const u32* sp = sorted + (size_t)b * CAP;

    // phase A: read edges (coalesced), LDS-histogram, remember slots in regs
    u32 ev[8];
    int rv[8], sl[8];
#pragma unroll
    for (int q = 0; q < 8; ++q) {
        int i = tid + q * AGG_T;
        ev[q] = (i < cnt) ? sp[i] : 0xFFFFFFFFu;    // valid entries < 196<<17
    }
#pragma unroll
    for (int q = 0; q < 8; ++q) {
        if (ev[q] != 0xFFFFFFFFu) {
            rv[q] = (int)(ev[q] >> 17);
            sl[q] = (int)atomicAdd(&hist[rv[q]], 1u);
        }
    }
    __syncthreads();

    // phase B: copy hist->deg, inclusive Hillis-Steele scan, make exclusive
    if (tid < B_NODES) { deg[tid] = hist[tid]; offs[tid] = hist[tid]; }
    __syncthreads();
#pragma unroll
    for (int s = 1; s < B_NODES; s <<= 1) {
        u32 v = 0;
        if (tid < B_NODES && tid >= s) v = offs[tid - s];
        __syncthreads();
        if (tid < B_NODES) offs[tid] += v;
        __syncthreads();
    }
    if (tid < B_NODES) offs[tid] -= deg[tid];
    __syncthreads();

    // phase C: scatter srcs into per-node CSR segments in LDS
#pragma unroll
    for (int q = 0; q < 8; ++q) {
        if (ev[q] != 0xFFFFFFFFu)
            srcs[offs[rv[q]] + (u32)sl[q]] = ev[q] & 0x1FFFFu;
    }
    __syncthreads();

    // phase D: accumulate. threads [0,196) = portion 0, [196,392) = portion 1
    float a0 = 0.f, a1 = 0.f, a2 = 0.f, a3 = 0.f, a4 = 0.f;
    if (tid < 2 * B_NODES) {
        const int p = (tid >= B_NODES);
        const int n = p ? tid - B_NODES : tid;
        const u32 d = deg[n];
        const u32 o = offs[n];
        const u32 h0 = (d + 1) >> 1;
        const u32 i0 = p ? o + h0 : o;
        const u32 i1 = p ? o + d : o + h0;
        for (u32 i = i0; i < i1; ++i) {
            u32 s = srcs[i];
            uint4 h = hl[s];
            a0 += __half2float(__ushort_as_half((unsigned short)(h.x & 0xFFFFu)));
            a1 += __half2float(__ushort_as_half((unsigned short)(h.x >> 16)));
            a2 += __half2float(__ushort_as_half((unsigned short)(h.y & 0xFFFFu)));
            a3 += __half2float(__ushort_as_half((unsigned short)(h.y >> 16)));
            a4 += __half2float(__ushort_as_half((unsigned short)(h.z & 0xFFFFu)));
        }
        if (p) {
            part[n][0] = a0; part[n][1] = a1; part[n][2] = a2;
            part[n][3] = a3; part[n][4] = a4;
        }
    }
    __syncthreads();

    // phase E: combine portions, mean, add bias + hr, store
    if (tid < B_NODES) {
        const int node = b * B_NODES + tid;
        if (node < N_NODES) {
            a0 += part[tid][0]; a1 += part[tid][1]; a2 += part[tid][2];
            a3 += part[tid][3]; a4 += part[tid][4];
            const float rec = 1.0f / fmaxf((float)deg[tid], 1.0f);
            const float* h = hr + (size_t)node * HR_STRIDE;
            float* o = out + (size_t)node * 5;
            o[0] = a0 * rec + bias[0] + h[0];
            o[1] = a1 * rec + bias[1] + h[1];
            o[2] = a2 * rec + bias[2] + h[2];
            o[3] = a3 * rec + bias[3] + h[3];
            o[4] = a4 * rec + bias[4] + h[4];
        }
    }
}

extern "C" void kernel_launch(void* const* d_in, const int* in_sizes, int n_in,
                              void* d_out, int out_size, void* d_ws, size_t ws_size,
                              hipStream_t stream) {
    const float* x    = (const float*)d_in[0];
    const int*   ei   = (const int*)d_in[1];
    const float* Wl   = (const float*)d_in[2];
    const float* bl   = (const float*)d_in[3];
    const float* Wr   = (const float*)d_in[4];
    float*       out  = (float*)d_out;

    // workspace layout (16B-aligned): ~12.7 MB total
    uint4* hl     = (uint4*)d_ws;                                 // N_PAD*16 B
    float* hr     = (float*)(hl + N_PAD);                         // N_PAD*8 f
    u32*   sorted = (u32*)(hr + (size_t)N_PAD * HR_STRIDE);       // 512*3840 u32
    int*   cursor = (int*)(sorted + (size_t)N_BUCKETS * CAP);     // 512 i32

    hipMemsetAsync(cursor, 0, N_BUCKETS * sizeof(int), stream);

    proj_scatter_kernel<<<FUSED_GRID, 256, 0, stream>>>(
        x, Wl, Wr, hl, hr, ei, sorted, cursor);

    agg_kernel<<<N_BUCKETS, 512, 0, stream>>>(sorted, cursor, hl, hr, bl, out);
}

// Round 7
// 126.979 us; speedup vs baseline: 1.2106x; 1.0377x over previous
//
#include <hip/hip_runtime.h>
#include <hip/hip_fp16.h>

// SAGEConv mean-aggr: out_i = mean_{j->i} x_j @ W_l^T + b_l + x_i @ W_r^T
//
// R1-R9: 481 -> 132.45 us (counting-sort buckets + LDS u64 atomics, VGPR
//        weights, 2-blocks/CU agg).
// R10: hl as 8xfp16 -> neutral (agg not gather-bound).
// R11: fused proj+scatter 2:1 interleave, EPT16 -> 127.7 us. BEST.
// R12: DMA-staged proj -> neutral. Proj never moves fused-A (rides under
//      scatter). R13: 3-way split -> 153.7 REGRESSION (serial dispatches).
// R14/R15: R11 fused-A + CSR-sort agg -> 131.8: CSR agg is ~4 us WORSE
//      than u64-atomic agg (scan barriers + serial phase-D). Agg verdict:
//      LDS-atomic-THROUGHPUT bound (R10 gather-halving null).
// R16: cut agg to 2 u64 atomics/edge: fixed-point scale 2^8, bias 2^14,
//      21-bit fields {d0,d1,d2 | d3,d4,deg}. Added rounding err 2e-3 ==
//      magnitude of the fp16-hl err already proven invisible. accA/accB as
//      SEPARATE stride-8B arrays to keep 16-bank spread per op (single
//      stride-16 array would halve the spread and eat the win).

#define N_NODES 100000
#define N_EDGES 1600000
#define D_IN 128

#define HR_STRIDE 8
#define N_PAD 100352                   // padded node count

#define B_NODES 196                    // nodes per bucket
#define N_BUCKETS 512                  // 512*196 = 100352 >= N_NODES
#define CAP 3840                       // mean 3125, sigma ~56 -> +12.8 sigma

#define SC_EPT 16
#define SC_EPB (256 * SC_EPT)          // 4096 edges per scatter block
#define SC_GRID ((N_EDGES + SC_EPB - 1) / SC_EPB)   // 391

#define PROJ_NPB 128                   // nodes per proj block
#define PROJ_BLOCKS ((N_NODES + PROJ_NPB - 1) / PROJ_NPB)   // 782
// interleave 2 proj : 1 scatter; PROJ_BLOCKS == 2*SC_GRID == 782
#define FUSED_GRID (PROJ_BLOCKS + SC_GRID)                  // 1173

// fixed-point: field = f*2^8 + 2^14 per addend, 21-bit field sums.
// |f|<=32 -> addend <= 24576; deg<=85 keeps every field < 2^21 (max deg ~45).
#define FX2S 256.0f
#define FX2B 16384u
#define FX2BF 16384.0f
#define INV_FX2S (1.0f / 256.0f)
#define FMASK 0x1FFFFFu

typedef unsigned long long u64;
typedef unsigned int u32;

__device__ __forceinline__ float dot8(const float4 a0, const float4 a1,
                                      const float4 b0, const float4 b1) {
    return a0.x * b0.x + a0.y * b0.y + a0.z * b0.z + a0.w * b0.w
         + a1.x * b1.x + a1.y * b1.y + a1.z * b1.z + a1.w * b1.w;
}

// ---------------------------------------------------------------------------
// Fused kernel A: interleaved projection (2 of 3 blocks) + counting-sort
// scatter (1 of 3). Exactly the R11 kernel (measured 41.28 us). DO NOT TOUCH.
// ---------------------------------------------------------------------------
__global__ __launch_bounds__(256, 4) void proj_scatter_kernel(
    const float* __restrict__ x,
    const float* __restrict__ Wl,
    const float* __restrict__ Wr,
    uint4* __restrict__ hl,             // [N_PAD] 8xfp16 packed, first 5 valid
    float* __restrict__ hr,             // [N_PAD][8] f32, first 5 valid
    const int* __restrict__ ei,         // [2][N_EDGES]: row0 src, row1 dst
    u32* __restrict__ sorted,           // [N_BUCKETS][CAP]
    int* __restrict__ cursor)           // [N_BUCKETS], zero-initialized
{
    const int tid = threadIdx.x;
    const int m   = blockIdx.x % 3;
    const int d   = blockIdx.x / 3;

    if (m < 2) {
        // ---------------- projection ----------------
        const int pidx = d * 2 + m;      // 0..781
        const int g = tid >> 4;          // group 0..15
        const int k = tid & 15;          // lane within group, dims [8k,8k+8)
        const int node0 = pidx * PROJ_NPB + g * 8;

#pragma unroll
        for (int hb = 0; hb < 2; ++hb) {
            const int nb = node0 + hb * 4;

            float4 xv[4][2];
            int nodes[4];
#pragma unroll
            for (int it = 0; it < 4; ++it) {
                nodes[it] = min(nb + it, N_NODES - 1);
                const float4* xr =
                    (const float4*)(x + (size_t)nodes[it] * D_IN + k * 8);
                xv[it][0] = xr[0];
                xv[it][1] = xr[1];
            }

            // Wl pass
            {
                float4 wv[5][2];
#pragma unroll
                for (int o = 0; o < 5; ++o) {
                    const float* w = Wl + o * D_IN + k * 8;
                    wv[o][0] = ((const float4*)w)[0];
                    wv[o][1] = ((const float4*)w)[1];
                }
#pragma unroll
                for (int it = 0; it < 4; ++it) {
                    float s[5];
#pragma unroll
                    for (int o = 0; o < 5; ++o)
                        s[o] = dot8(xv[it][0], xv[it][1], wv[o][0], wv[o][1]);
#pragma unroll
                    for (int o = 0; o < 5; ++o) {
                        s[o] += __shfl_xor(s[o], 8, 64);
                        s[o] += __shfl_xor(s[o], 4, 64);
                        s[o] += __shfl_xor(s[o], 2, 64);
                        s[o] += __shfl_xor(s[o], 1, 64);
                    }
                    if (k == 0) {
                        u32 u0 = (u32)__half_as_ushort(__float2half_rn(s[0]));
                        u32 u1 = (u32)__half_as_ushort(__float2half_rn(s[1]));
                        u32 u2 = (u32)__half_as_ushort(__float2half_rn(s[2]));
                        u32 u3 = (u32)__half_as_ushort(__float2half_rn(s[3]));
                        u32 u4 = (u32)__half_as_ushort(__float2half_rn(s[4]));
                        uint4 pk;
                        pk.x = u0 | (u1 << 16);
                        pk.y = u2 | (u3 << 16);
                        pk.z = u4;
                        pk.w = 0u;
                        hl[nodes[it]] = pk;
                    }
                }
            }

            // Wr pass
            {
                float4 wv[5][2];
#pragma unroll
                for (int o = 0; o < 5; ++o) {
                    const float* w = Wr + o * D_IN + k * 8;
                    wv[o][0] = ((const float4*)w)[0];
                    wv[o][1] = ((const float4*)w)[1];
                }
#pragma unroll
                for (int it = 0; it < 4; ++it) {
                    float s[5];
#pragma unroll
                    for (int o = 0; o < 5; ++o)
                        s[o] = dot8(xv[it][0], xv[it][1], wv[o][0], wv[o][1]);
#pragma unroll
                    for (int o = 0; o < 5; ++o) {
                        s[o] += __shfl_xor(s[o], 8, 64);
                        s[o] += __shfl_xor(s[o], 4, 64);
                        s[o] += __shfl_xor(s[o], 2, 64);
                        s[o] += __shfl_xor(s[o], 1, 64);
                    }
                    if (k == 0) {
                        float* pr = hr + (size_t)nodes[it] * HR_STRIDE;
                        *(float4*)pr = make_float4(s[0], s[1], s[2], s[3]);
                        pr[4] = s[4];
                    }
                }
            }
        }
    } else {
        // ---------------- counting-sort scatter ----------------
        __shared__ int hist[N_BUCKETS];
        __shared__ int basepos[N_BUCKETS];

        for (int i = tid; i < N_BUCKETS; i += 256) hist[i] = 0;
        __syncthreads();

        const int e0 = d * SC_EPB + tid * SC_EPT;

        int srcv[SC_EPT], dstv[SC_EPT], slot[SC_EPT];
        bool valid[SC_EPT];

        if (e0 + SC_EPT <= N_EDGES) {
            const int4* s4 = (const int4*)(ei + e0);
            const int4* d4 = (const int4*)(ei + N_EDGES + e0);
#pragma unroll
            for (int c = 0; c < SC_EPT / 4; ++c) {
                int4 sv = s4[c], dv = d4[c];
                srcv[c*4+0] = sv.x; srcv[c*4+1] = sv.y;
                srcv[c*4+2] = sv.z; srcv[c*4+3] = sv.w;
                dstv[c*4+0] = dv.x; dstv[c*4+1] = dv.y;
                dstv[c*4+2] = dv.z; dstv[c*4+3] = dv.w;
            }
#pragma unroll
            for (int q = 0; q < SC_EPT; ++q) valid[q] = true;
        } else {
#pragma unroll
            for (int q = 0; q < SC_EPT; ++q) {
                int e = e0 + q;
                valid[q] = (e < N_EDGES);
                srcv[q] = valid[q] ? ei[e] : 0;
                dstv[q] = valid[q] ? ei[N_EDGES + e] : 0;
            }
        }

#pragma unroll
        for (int q = 0; q < SC_EPT; ++q) {
            if (valid[q]) {
                unsigned b = (unsigned)dstv[q] / 196u;   // magic-mul div
                slot[q] = atomicAdd(&hist[b], 1);
            }
        }
        __syncthreads();

        for (int b = tid; b < N_BUCKETS; b += 256) {
            int c = hist[b];
            if (c > 0) basepos[b] = atomicAdd(&cursor[b], c);
        }
        __syncthreads();

#pragma unroll
        for (int q = 0; q < SC_EPT; ++q) {
            if (valid[q]) {
                unsigned b = (unsigned)dstv[q] / 196u;
                unsigned r = (unsigned)dstv[q] - b * 196u;
                sorted[(size_t)b * CAP + basepos[b] + slot[q]] =
                    (r << 17) | (unsigned)srcv[q];
            }
        }
    }
}

// ---------------------------------------------------------------------------
// Kernel B: per-bucket aggregation, TWO u64 LDS atomics per edge.
// Fields: accA = d0|d1<<21|d2<<42, accB = d3|d4<<21|deg<<42 (21-bit sums).
// Separate stride-8B arrays keep 16-bank spread per atomic.
// ---------------------------------------------------------------------------
__global__ __launch_bounds__(512) void agg_kernel(
    const u32* __restrict__ sorted,
    const int* __restrict__ cursor,
    const uint4* __restrict__ hl,
    const float* __restrict__ hr,
    const float* __restrict__ bias,
    float* __restrict__ out)
{
    __shared__ u64 accA[B_NODES];      // 1.6 KB
    __shared__ u64 accB[B_NODES];      // 1.6 KB

    const int b   = blockIdx.x;
    const int tid = threadIdx.x;

    for (int i = tid; i < B_NODES; i += 512) { accA[i] = 0ull; accB[i] = 0ull; }
    __syncthreads();

    const int cnt = cursor[b];
    const u32* sp = sorted + (size_t)b * CAP;
    const int nvec = cnt >> 2;

#define EMITH(hv, rr)                                                        \
    {                                                                        \
        float g0 = __half2float(__ushort_as_half((unsigned short)((hv).x & 0xFFFFu))); \
        float g1 = __half2float(__ushort_as_half((unsigned short)((hv).x >> 16)));     \
        float g2 = __half2float(__ushort_as_half((unsigned short)((hv).y & 0xFFFFu))); \
        float g3 = __half2float(__ushort_as_half((unsigned short)((hv).y >> 16)));     \
        float g4 = __half2float(__ushort_as_half((unsigned short)((hv).z & 0xFFFFu))); \
        u32 f0 = __float2uint_rn(fmaf(g0, FX2S, FX2BF));                     \
        u32 f1 = __float2uint_rn(fmaf(g1, FX2S, FX2BF));                     \
        u32 f2 = __float2uint_rn(fmaf(g2, FX2S, FX2BF));                     \
        u32 f3 = __float2uint_rn(fmaf(g3, FX2S, FX2BF));                     \
        u32 f4 = __float2uint_rn(fmaf(g4, FX2S, FX2BF));                     \
        atomicAdd(&accA[rr], (u64)f0 | ((u64)f1 << 21) | ((u64)f2 << 42));   \
        atomicAdd(&accB[rr], (u64)f3 | ((u64)f4 << 21) | (1ull << 42));      \
    }

    for (int it = tid; it < nvec; it += 512) {
        uint4 v = ((const uint4*)sp)[it];
        int s0 = (int)(v.x & 0x1FFFFu), r0 = (int)(v.x >> 17);
        int s1 = (int)(v.y & 0x1FFFFu), r1 = (int)(v.y >> 17);
        int s2 = (int)(v.z & 0x1FFFFu), r2 = (int)(v.z >> 17);
        int s3 = (int)(v.w & 0x1FFFFu), r3 = (int)(v.w >> 17);

        uint4 a0 = hl[s0];
        uint4 a1 = hl[s1];
        uint4 a2 = hl[s2];
        uint4 a3 = hl[s3];

        EMITH(a0, r0) EMITH(a1, r1) EMITH(a2, r2) EMITH(a3, r3)
    }
    for (int i = (nvec << 2) + tid; i < cnt; i += 512) {
        u32 v = sp[i];
        int src = (int)(v & 0x1FFFFu);
        int r   = (int)(v >> 17);
        uint4 a = hl[src];
        EMITH(a, r)
    }
#undef EMITH
    __syncthreads();

    const int nodebase = b * B_NODES;
    for (int n = tid; n < B_NODES; n += 512) {
        int node = nodebase + n;
        if (node >= N_NODES) continue;
        u64 wA = accA[n];
        u64 wB = accB[n];
        u32 deg = (u32)(wB >> 42);
        u32 db  = deg * FX2B;           // <= 85*16384 < 2^21, no wrap
        int i0 = (int)((u32)(wA        & FMASK) - db);
        int i1 = (int)((u32)((wA >> 21) & FMASK) - db);
        int i2 = (int)((u32)((wA >> 42) & FMASK) - db);
        int i3 = (int)((u32)(wB        & FMASK) - db);
        int i4 = (int)((u32)((wB >> 21) & FMASK) - db);

        float rec = INV_FX2S / fmaxf((float)deg, 1.0f);
        const float* h = hr + (size_t)node * HR_STRIDE;
        float* o = out + (size_t)node * 5;
        o[0] = (float)i0 * rec + bias[0] + h[0];
        o[1] = (float)i1 * rec + bias[1] + h[1];
        o[2] = (float)i2 * rec + bias[2] + h[2];
        o[3] = (float)i3 * rec + bias[3] + h[3];
        o[4] = (float)i4 * rec + bias[4] + h[4];
    }
}

extern "C" void kernel_launch(void* const* d_in, const int* in_sizes, int n_in,
                              void* d_out, int out_size, void* d_ws, size_t ws_size,
                              hipStream_t stream) {
    const float* x    = (const float*)d_in[0];
    const int*   ei   = (const int*)d_in[1];
    const float* Wl   = (const float*)d_in[2];
    const float* bl   = (const float*)d_in[3];
    const float* Wr   = (const float*)d_in[4];
    float*       out  = (float*)d_out;

    // workspace layout (16B-aligned): ~12.7 MB total
    uint4* hl     = (uint4*)d_ws;                                 // N_PAD*16 B
    float* hr     = (float*)(hl + N_PAD);                         // N_PAD*8 f
    u32*   sorted = (u32*)(hr + (size_t)N_PAD * HR_STRIDE);       // 512*3840 u32
    int*   cursor = (int*)(sorted + (size_t)N_BUCKETS * CAP);     // 512 i32

    hipMemsetAsync(cursor, 0, N_BUCKETS * sizeof(int), stream);

    proj_scatter_kernel<<<FUSED_GRID, 256, 0, stream>>>(
        x, Wl, Wr, hl, hr, ei, sorted, cursor);

    agg_kernel<<<N_BUCKETS, 512, 0, stream>>>(sorted, cursor, hl, hr, bl, out);
}

// Round 8
// 125.810 us; speedup vs baseline: 1.2218x; 1.0093x over previous
//
#include <hip/hip_runtime.h>
#include <hip/hip_fp16.h>

// SAGEConv mean-aggr: out_i = mean_{j->i} x_j @ W_l^T + b_l + x_i @ W_r^T
//
// R1-R9: 481 -> 132.45 us (counting-sort buckets + LDS u64 atomics, VGPR
//        weights, 2-blocks/CU agg).
// R10: hl as 8xfp16 -> neutral (agg not gather-bound).
// R11: fused proj+scatter 2:1 interleave, EPT16 -> 127.7 us.
// R12: DMA-staged proj -> neutral. R13: 3-way split -> 153.7 (serialized).
// R14/R15: CSR agg -> +4 us vs atomic agg. R16: 2 u64 atomics/edge
//      (21-bit fields) -> 126.98. Agg inner-loop insensitive overall.
// DIAGNOSIS CLOSED (R17): fused-A moves 58.5 MB HBM in 41.3 us = its
//      measured 1.45 TB/s -> A is HBM-BYTE-bound. sorted writes: 6.4 MB
//      payload -> ~26 MB HBM (scattered 4B stores, partial-line + write-
//      allocate amplification). That's why ILP/DMA experiments were null.
// R17: block-local LDS reorder before the sorted write: exclusive scan of
//      hist -> stage 4096 edges bucket-ordered in LDS (ordbuf) + global
//      index (gidx) -> linear writer loop: consecutive lanes hit
//      consecutive addresses within each bucket run (~8-entry segments
//      instead of 64 scattered dwords/wave). LDS 39KB, still 4 blocks/CU.

#define N_NODES 100000
#define N_EDGES 1600000
#define D_IN 128

#define HR_STRIDE 8
#define N_PAD 100352                   // padded node count

#define B_NODES 196                    // nodes per bucket
#define N_BUCKETS 512                  // 512*196 = 100352 >= N_NODES
#define CAP 3840                       // mean 3125, sigma ~56 -> +12.8 sigma

#define SC_EPT 16
#define SC_EPB (256 * SC_EPT)          // 4096 edges per scatter block
#define SC_GRID ((N_EDGES + SC_EPB - 1) / SC_EPB)   // 391

#define PROJ_NPB 128                   // nodes per proj block
#define PROJ_BLOCKS ((N_NODES + PROJ_NPB - 1) / PROJ_NPB)   // 782
// interleave 2 proj : 1 scatter; PROJ_BLOCKS == 2*SC_GRID == 782
#define FUSED_GRID (PROJ_BLOCKS + SC_GRID)                  // 1173

// fixed-point: field = f*2^8 + 2^14 per addend, 21-bit field sums.
#define FX2S 256.0f
#define FX2B 16384u
#define FX2BF 16384.0f
#define INV_FX2S (1.0f / 256.0f)
#define FMASK 0x1FFFFFu

typedef unsigned long long u64;
typedef unsigned int u32;

__device__ __forceinline__ float dot8(const float4 a0, const float4 a1,
                                      const float4 b0, const float4 b1) {
    return a0.x * b0.x + a0.y * b0.y + a0.z * b0.z + a0.w * b0.w
         + a1.x * b1.x + a1.y * b1.y + a1.z * b1.z + a1.w * b1.w;
}

// ---------------------------------------------------------------------------
// Fused kernel A: interleaved projection (2 of 3 blocks) + counting-sort
// scatter with LDS write-reorder (1 of 3).
// ---------------------------------------------------------------------------
__global__ __launch_bounds__(256, 4) void proj_scatter_kernel(
    const float* __restrict__ x,
    const float* __restrict__ Wl,
    const float* __restrict__ Wr,
    uint4* __restrict__ hl,             // [N_PAD] 8xfp16 packed, first 5 valid
    float* __restrict__ hr,             // [N_PAD][8] f32, first 5 valid
    const int* __restrict__ ei,         // [2][N_EDGES]: row0 src, row1 dst
    u32* __restrict__ sorted,           // [N_BUCKETS][CAP]
    int* __restrict__ cursor)           // [N_BUCKETS], zero-initialized
{
    const int tid = threadIdx.x;
    const int m   = blockIdx.x % 3;
    const int d   = blockIdx.x / 3;

    if (m < 2) {
        // ---------------- projection (exact R11 code) ----------------
        const int pidx = d * 2 + m;      // 0..781
        const int g = tid >> 4;          // group 0..15
        const int k = tid & 15;          // lane within group, dims [8k,8k+8)
        const int node0 = pidx * PROJ_NPB + g * 8;

#pragma unroll
        for (int hb = 0; hb < 2; ++hb) {
            const int nb = node0 + hb * 4;

            float4 xv[4][2];
            int nodes[4];
#pragma unroll
            for (int it = 0; it < 4; ++it) {
                nodes[it] = min(nb + it, N_NODES - 1);
                const float4* xr =
                    (const float4*)(x + (size_t)nodes[it] * D_IN + k * 8);
                xv[it][0] = xr[0];
                xv[it][1] = xr[1];
            }

            // Wl pass
            {
                float4 wv[5][2];
#pragma unroll
                for (int o = 0; o < 5; ++o) {
                    const float* w = Wl + o * D_IN + k * 8;
                    wv[o][0] = ((const float4*)w)[0];
                    wv[o][1] = ((const float4*)w)[1];
                }
#pragma unroll
                for (int it = 0; it < 4; ++it) {
                    float s[5];
#pragma unroll
                    for (int o = 0; o < 5; ++o)
                        s[o] = dot8(xv[it][0], xv[it][1], wv[o][0], wv[o][1]);
#pragma unroll
                    for (int o = 0; o < 5; ++o) {
                        s[o] += __shfl_xor(s[o], 8, 64);
                        s[o] += __shfl_xor(s[o], 4, 64);
                        s[o] += __shfl_xor(s[o], 2, 64);
                        s[o] += __shfl_xor(s[o], 1, 64);
                    }
                    if (k == 0) {
                        u32 u0 = (u32)__half_as_ushort(__float2half_rn(s[0]));
                        u32 u1 = (u32)__half_as_ushort(__float2half_rn(s[1]));
                        u32 u2 = (u32)__half_as_ushort(__float2half_rn(s[2]));
                        u32 u3 = (u32)__half_as_ushort(__float2half_rn(s[3]));
                        u32 u4 = (u32)__half_as_ushort(__float2half_rn(s[4]));
                        uint4 pk;
                        pk.x = u0 | (u1 << 16);
                        pk.y = u2 | (u3 << 16);
                        pk.z = u4;
                        pk.w = 0u;
                        hl[nodes[it]] = pk;
                    }
                }
            }

            // Wr pass
            {
                float4 wv[5][2];
#pragma unroll
                for (int o = 0; o < 5; ++o) {
                    const float* w = Wr + o * D_IN + k * 8;
                    wv[o][0] = ((const float4*)w)[0];
                    wv[o][1] = ((const float4*)w)[1];
                }
#pragma unroll
                for (int it = 0; it < 4; ++it) {
                    float s[5];
#pragma unroll
                    for (int o = 0; o < 5; ++o)
                        s[o] = dot8(xv[it][0], xv[it][1], wv[o][0], wv[o][1]);
#pragma unroll
                    for (int o = 0; o < 5; ++o) {
                        s[o] += __shfl_xor(s[o], 8, 64);
                        s[o] += __shfl_xor(s[o], 4, 64);
                        s[o] += __shfl_xor(s[o], 2, 64);
                        s[o] += __shfl_xor(s[o], 1, 64);
                    }
                    if (k == 0) {
                        float* pr = hr + (size_t)nodes[it] * HR_STRIDE;
                        *(float4*)pr = make_float4(s[0], s[1], s[2], s[3]);
                        pr[4] = s[4];
                    }
                }
            }
        }
    } else {
        // -------- counting-sort scatter with LDS write-reorder --------
        __shared__ int hist[N_BUCKETS];     // 2 KB  per-block bucket counts
        __shared__ int basepos[N_BUCKETS];  // 2 KB  global reservations
        __shared__ int lofs[N_BUCKETS];     // 2 KB  block-local excl. offsets
        __shared__ int s2[256];             // 1 KB  pair-sum scan buffer
        __shared__ u32 ordbuf[SC_EPB];      // 16 KB bucket-ordered payloads
        __shared__ u32 gidx[SC_EPB];        // 16 KB global indices

        for (int i = tid; i < N_BUCKETS; i += 256) hist[i] = 0;
        __syncthreads();

        const int e0 = d * SC_EPB + tid * SC_EPT;

        int srcv[SC_EPT], dstv[SC_EPT], slot[SC_EPT];
        bool valid[SC_EPT];

        if (e0 + SC_EPT <= N_EDGES) {
            const int4* s4 = (const int4*)(ei + e0);
            const int4* d4 = (const int4*)(ei + N_EDGES + e0);
#pragma unroll
            for (int c = 0; c < SC_EPT / 4; ++c) {
                int4 sv = s4[c], dv = d4[c];
                srcv[c*4+0] = sv.x; srcv[c*4+1] = sv.y;
                srcv[c*4+2] = sv.z; srcv[c*4+3] = sv.w;
                dstv[c*4+0] = dv.x; dstv[c*4+1] = dv.y;
                dstv[c*4+2] = dv.z; dstv[c*4+3] = dv.w;
            }
#pragma unroll
            for (int q = 0; q < SC_EPT; ++q) valid[q] = true;
        } else {
#pragma unroll
            for (int q = 0; q < SC_EPT; ++q) {
                int e = e0 + q;
                valid[q] = (e < N_EDGES);
                srcv[q] = valid[q] ? ei[e] : 0;
                dstv[q] = valid[q] ? ei[N_EDGES + e] : 0;
            }
        }

#pragma unroll
        for (int q = 0; q < SC_EPT; ++q) {
            if (valid[q]) {
                unsigned b = (unsigned)dstv[q] / 196u;   // magic-mul div
                slot[q] = atomicAdd(&hist[b], 1);        // block-local rank
            }
        }
        __syncthreads();

        // global reservation per bucket (one atomic per nonempty bucket)
        for (int b = tid; b < N_BUCKETS; b += 256) {
            int c = hist[b];
            if (c > 0) basepos[b] = atomicAdd(&cursor[b], c);
        }

        // block-local exclusive scan of hist (512) via 256 pair-sums
        s2[tid] = hist[2 * tid] + hist[2 * tid + 1];
        __syncthreads();
#pragma unroll
        for (int s = 1; s < 256; s <<= 1) {
            int v = (tid >= s) ? s2[tid - s] : 0;
            __syncthreads();
            s2[tid] += v;
            __syncthreads();
        }
        {
            int e = (tid > 0) ? s2[tid - 1] : 0;
            lofs[2 * tid]     = e;
            lofs[2 * tid + 1] = e + hist[2 * tid];
        }
        __syncthreads();

        const int total = s2[255];

        // stage edges bucket-ordered in LDS, with their global index
#pragma unroll
        for (int q = 0; q < SC_EPT; ++q) {
            if (valid[q]) {
                unsigned b = (unsigned)dstv[q] / 196u;
                unsigned r = (unsigned)dstv[q] - b * 196u;
                int lp = lofs[b] + slot[q];
                ordbuf[lp] = (r << 17) | (unsigned)srcv[q];
                gidx[lp]   = (u32)b * CAP + (u32)basepos[b] + (u32)slot[q];
            }
        }
        __syncthreads();

        // linear writer: consecutive lanes -> consecutive addresses within
        // each bucket run (~8-entry segments instead of 64 scattered dwords)
        for (int i = tid; i < total; i += 256)
            sorted[gidx[i]] = ordbuf[i];
    }
}

// ---------------------------------------------------------------------------
// Kernel B: per-bucket aggregation, TWO u64 LDS atomics per edge (R16).
// ---------------------------------------------------------------------------
__global__ __launch_bounds__(512) void agg_kernel(
    const u32* __restrict__ sorted,
    const int* __restrict__ cursor,
    const uint4* __restrict__ hl,
    const float* __restrict__ hr,
    const float* __restrict__ bias,
    float* __restrict__ out)
{
    __shared__ u64 accA[B_NODES];      // 1.6 KB
    __shared__ u64 accB[B_NODES];      // 1.6 KB

    const int b   = blockIdx.x;
    const int tid = threadIdx.x;

    for (int i = tid; i < B_NODES; i += 512) { accA[i] = 0ull; accB[i] = 0ull; }
    __syncthreads();

    const int cnt = cursor[b];
    const u32* sp = sorted + (size_t)b * CAP;
    const int nvec = cnt >> 2;

#define EMITH(hv, rr)                                                        \
    {                                                                        \
        float g0 = __half2float(__ushort_as_half((unsigned short)((hv).x & 0xFFFFu))); \
        float g1 = __half2float(__ushort_as_half((unsigned short)((hv).x >> 16)));     \
        float g2 = __half2float(__ushort_as_half((unsigned short)((hv).y & 0xFFFFu))); \
        float g3 = __half2float(__ushort_as_half((unsigned short)((hv).y >> 16)));     \
        float g4 = __half2float(__ushort_as_half((unsigned short)((hv).z & 0xFFFFu))); \
        u32 f0 = __float2uint_rn(fmaf(g0, FX2S, FX2BF));                     \
        u32 f1 = __float2uint_rn(fmaf(g1, FX2S, FX2BF));                     \
        u32 f2 = __float2uint_rn(fmaf(g2, FX2S, FX2BF));                     \
        u32 f3 = __float2uint_rn(fmaf(g3, FX2S, FX2BF));                     \
        u32 f4 = __float2uint_rn(fmaf(g4, FX2S, FX2BF));                     \
        atomicAdd(&accA[rr], (u64)f0 | ((u64)f1 << 21) | ((u64)f2 << 42));   \
        atomicAdd(&accB[rr], (u64)f3 | ((u64)f4 << 21) | (1ull << 42));      \
    }

    for (int it = tid; it < nvec; it += 512) {
        uint4 v = ((const uint4*)sp)[it];
        int s0 = (int)(v.x & 0x1FFFFu), r0 = (int)(v.x >> 17);
        int s1 = (int)(v.y & 0x1FFFFu), r1 = (int)(v.y >> 17);
        int s2 = (int)(v.z & 0x1FFFFu), r2 = (int)(v.z >> 17);
        int s3 = (int)(v.w & 0x1FFFFu), r3 = (int)(v.w >> 17);

        uint4 a0 = hl[s0];
        uint4 a1 = hl[s1];
        uint4 a2 = hl[s2];
        uint4 a3 = hl[s3];

        EMITH(a0, r0) EMITH(a1, r1) EMITH(a2, r2) EMITH(a3, r3)
    }
    for (int i = (nvec << 2) + tid; i < cnt; i += 512) {
        u32 v = sp[i];
        int src = (int)(v & 0x1FFFFu);
        int r   = (int)(v >> 17);
        uint4 a = hl[src];
        EMITH(a, r)
    }
#undef EMITH
    __syncthreads();

    const int nodebase = b * B_NODES;
    for (int n = tid; n < B_NODES; n += 512) {
        int node = nodebase + n;
        if (node >= N_NODES) continue;
        u64 wA = accA[n];
        u64 wB = accB[n];
        u32 deg = (u32)(wB >> 42);
        u32 db  = deg * FX2B;           // <= 85*16384 < 2^21, no wrap
        int i0 = (int)((u32)(wA        & FMASK) - db);
        int i1 = (int)((u32)((wA >> 21) & FMASK) - db);
        int i2 = (int)((u32)((wA >> 42) & FMASK) - db);
        int i3 = (int)((u32)(wB        & FMASK) - db);
        int i4 = (int)((u32)((wB >> 21) & FMASK) - db);

        float rec = INV_FX2S / fmaxf((float)deg, 1.0f);
        const float* h = hr + (size_t)node * HR_STRIDE;
        float* o = out + (size_t)node * 5;
        o[0] = (float)i0 * rec + bias[0] + h[0];
        o[1] = (float)i1 * rec + bias[1] + h[1];
        o[2] = (float)i2 * rec + bias[2] + h[2];
        o[3] = (float)i3 * rec + bias[3] + h[3];
        o[4] = (float)i4 * rec + bias[4] + h[4];
    }
}

extern "C" void kernel_launch(void* const* d_in, const int* in_sizes, int n_in,
                              void* d_out, int out_size, void* d_ws, size_t ws_size,
                              hipStream_t stream) {
    const float* x    = (const float*)d_in[0];
    const int*   ei   = (const int*)d_in[1];
    const float* Wl   = (const float*)d_in[2];
    const float* bl   = (const float*)d_in[3];
    const float* Wr   = (const float*)d_in[4];
    float*       out  = (float*)d_out;

    // workspace layout (16B-aligned): ~12.7 MB total
    uint4* hl     = (uint4*)d_ws;                                 // N_PAD*16 B
    float* hr     = (float*)(hl + N_PAD);                         // N_PAD*8 f
    u32*   sorted = (u32*)(hr + (size_t)N_PAD * HR_STRIDE);       // 512*3840 u32
    int*   cursor = (int*)(sorted + (size_t)N_BUCKETS * CAP);     // 512 i32

    hipMemsetAsync(cursor, 0, N_BUCKETS * sizeof(int), stream);

    proj_scatter_kernel<<<FUSED_GRID, 256, 0, stream>>>(
        x, Wl, Wr, hl, hr, ei, sorted, cursor);

    agg_kernel<<<N_BUCKETS, 512, 0, stream>>>(sorted, cursor, hl, hr, bl, out);
}